// Round 1
// baseline (1638.109 us; speedup 1.0000x reference)
//
#include <hip/hip_runtime.h>

// ColorDeformConv2d on MI355X — round 1: correct fp32 mega-kernel, zero workspace.
// B=4, C=64, H=W=128, OUTC=64, KS=3, N=9, pad=1, stride=1.
//
// Per block: 8x8 pixel tile, 256 threads.
//  Phase 0: compute fused (1x1 conv of concat(x,ref)) on 10x10 halo tile in LDS.
//  Phase 1: 27-ch 3x3 conv (offset 18 + mask 9) per pixel.
//  Phase 1b: sampling positions -> bilinear idx/weight tables + sigmoid(m) in LDS.
//  Phase 2: main loop over 4 chunks of 16 c:
//    step A: 576-ch 3x3 conv (9 n per thread, 2x2 pixel quad) + tanh + bilinear
//            sample + modulate -> A values in registers
//    step B: per-c exchange through LDS, contract with w_conv into 16 out-accs/thread.

__device__ __forceinline__ float fast_rcp(float x) {
#if __has_builtin(__builtin_amdgcn_rcpf)
    return __builtin_amdgcn_rcpf(x);
#else
    return 1.0f / x;
#endif
}
__device__ __forceinline__ float fast_tanh(float x) {
    float t = __expf(2.0f * x);
    return 1.0f - 2.0f * fast_rcp(t + 1.0f);   // safe at t=inf -> 1, t=0 -> -1
}
__device__ __forceinline__ float fast_sigmoid(float x) {
    return fast_rcp(1.0f + __expf(-x));
}

__device__ __forceinline__ short mkidx(int r, int c) {
    // padded coords (Hp=Wp=130) -> flat idx into unpadded 128x128 plane, -1 if pad(0)
    return (r >= 1 && r <= 128 && c >= 1 && c <= 128) ? (short)(((r - 1) << 7) + (c - 1))
                                                      : (short)-1;
}

__global__ __launch_bounds__(256, 3)
void cdc_kernel(const float* __restrict__ x, const float* __restrict__ ref,
                const float* __restrict__ w_cd, const float* __restrict__ b_cd,
                const float* __restrict__ w_p, const float* __restrict__ b_p,
                const float* __restrict__ w_m, const float* __restrict__ b_m,
                const float* __restrict__ w_c, const float* __restrict__ b_c,
                const float* __restrict__ w_conv, float* __restrict__ out)
{
    __shared__ float fused_t[6400];                 // [ci=64][pos=100] 10x10 halo tile
    __shared__ __align__(16) char ublk[26496];      // time-multiplexed region

    // main-phase layout
    short* sidx   = (short*)ublk;                   // [64 pix][9 n][4]  (4608 B)
    float* sw4    = (float*)(ublk + 4608);          // [64 pix][9 n][4]  (9216 B)
    float* m_lds  = (float*)(ublk + 13824);         // [9 n][64 pix]     (2304 B)
    float* aslice = (float*)(ublk + 16128);         // [9 n][64 pix]     (2304 B)
    float* wcv    = (float*)(ublk + 18432);         // [64 oc][9 n]      (2304 B)
    float* wslice = (float*)(ublk + 20736);         // [144 row][9 tap]  (5184 B)
    // phase-0 layout (dead before sidx/sw4 written)
    float* xchunk = (float*)ublk;                   // [32][100]  (12800 B)
    float* wcds   = (float*)(ublk + 12800);         // [32][65]   (8320 B)
    // phase-1 layout (aliases m/aslice/wcv; m write order proven safe)
    float* u1     = (float*)(ublk + 13824);         // [27 ch][64 pix] (6912 B)

    const int tid = threadIdx.x;
    const int bb = blockIdx.z;
    const int h0 = blockIdx.y * 8;
    const int w0 = blockIdx.x * 8;
    const int pix = tid & 63;
    const int g = tid >> 6;            // wave id (wave-uniform)
    const int py = pix >> 3, px = pix & 7;

    // ---------------- Phase 0: fused 1x1 conv on halo tile ----------------
    #pragma unroll 1
    for (int sub = 0; sub < 4; ++sub) {
        const float* src = (sub < 2) ? x : ref;
        const int cbase = (sub & 1) * 32;
        for (int i = tid; i < 3200; i += 256) {
            int cl = i / 100, pos = i - cl * 100;
            int r = pos / 10, cc = pos - r * 10;
            int gh = h0 - 1 + r, gw = w0 - 1 + cc;
            float v = 0.0f;
            if ((unsigned)gh < 128u && (unsigned)gw < 128u)
                v = src[(((size_t)bb * 64 + cbase + cl) << 14) + (gh << 7) + gw];
            xchunk[i] = v;
        }
        const int wofs = ((sub < 2) ? 0 : 64) + cbase;
        for (int i = tid; i < 2048; i += 256) {
            int co = i >> 5, cl = i & 31;
            wcds[cl * 65 + co] = w_cd[(co << 7) + wofs + cl];
        }
        __syncthreads();
        {
            int co = tid & 63, pg = tid >> 6;
            #pragma unroll 1
            for (int pos = pg; pos < 100; pos += 4) {
                float acc;
                if (sub == 0) {
                    int r = pos / 10, cc = pos - r * 10;
                    int gh = h0 - 1 + r, gw = w0 - 1 + cc;
                    // fused at pad positions must be 0 (conv pad), not bias
                    acc = ((unsigned)gh < 128u && (unsigned)gw < 128u) ? b_cd[co] : 0.0f;
                } else {
                    acc = fused_t[co * 100 + pos];
                }
                #pragma unroll 8
                for (int cl = 0; cl < 32; ++cl)
                    acc += xchunk[cl * 100 + pos] * wcds[cl * 65 + co];
                fused_t[co * 100 + pos] = acc;
            }
        }
        __syncthreads();
    }

    // ---------------- Phase 1: 27-ch 3x3 conv (18 offset + 9 mask) ----------------
    {
        float a7[7];
        const float* wp7[7];
        #pragma unroll
        for (int k = 0; k < 7; ++k) {
            int ch = g + 4 * k;
            int chc = (ch < 27) ? ch : 26;          // clamp; result discarded
            wp7[k] = (chc < 18) ? (w_p + chc * 576) : (w_m + (chc - 18) * 576);
            a7[k] = (ch < 27) ? ((chc < 18) ? b_p[chc] : b_m[chc - 18]) : 0.0f;
        }
        #pragma unroll 1
        for (int ci = 0; ci < 64; ++ci) {
            const float* ft = &fused_t[ci * 100 + py * 10 + px];
            const int cofs = ci * 9;
            #pragma unroll
            for (int kh = 0; kh < 3; ++kh)
            #pragma unroll
            for (int kw = 0; kw < 3; ++kw) {
                float v = ft[kh * 10 + kw];
                int tofs = cofs + kh * 3 + kw;
                #pragma unroll
                for (int k = 0; k < 7; ++k)
                    a7[k] += v * wp7[k][tofs];
            }
        }
        #pragma unroll
        for (int k = 0; k < 7; ++k) {
            int ch = g + 4 * k;
            if (ch < 27) u1[ch * 64 + pix] = a7[k];
        }
    }
    __syncthreads();

    // ---------------- Phase 1b: bilinear tables + sigmoid(m) ----------------
    // m_lds aliases u1 ch 0..8; task (pp,n) is the unique reader of u1[n][pp] and
    // reads it before writing; pass n-groups (0-3, 4-7, 8) never cross -> safe.
    #pragma unroll 1
    for (int i = tid; i < 576; i += 256) {
        int pp = i & 63, n = i >> 6;
        int hh = h0 + (pp >> 3), ww = w0 + (pp & 7);
        float offr = u1[n * 64 + pp];
        float offc = u1[(9 + n) * 64 + pp];
        float mraw = u1[(18 + n) * 64 + pp];
        int nr = n / 3, nc = n - nr * 3;
        float pr = (float)(hh + nr) + offr;       // p0(=h+1) + pn(=nr-1) + off
        float pc = (float)(ww + nc) + offc;
        float flr = floorf(pr), flc = floorf(pc);
        float qltr = fminf(fmaxf(flr, 0.0f), 129.0f);
        float qrbr = fminf(fmaxf(flr + 1.0f, 0.0f), 129.0f);
        float qltc = fminf(fmaxf(flc, 0.0f), 129.0f);
        float qrbc = fminf(fmaxf(flc + 1.0f, 0.0f), 129.0f);
        float prc = fminf(fmaxf(pr, 0.0f), 129.0f);
        float pcc = fminf(fmaxf(pc, 0.0f), 129.0f);
        float wltr = 1.0f + qltr - prc, wrbr = 1.0f - (qrbr - prc);
        float wltc = 1.0f + qltc - pcc, wrbc = 1.0f - (qrbc - pcc);
        int iltr = (int)qltr, irbr = (int)qrbr, iltc = (int)qltc, irbc = (int)qrbc;
        short4 s4; float4 f4;
        s4.x = mkidx(iltr, iltc); f4.x = wltr * wltc;   // lt
        s4.y = mkidx(irbr, irbc); f4.y = wrbr * wrbc;   // rb
        s4.z = mkidx(iltr, irbc); f4.z = wltr * wrbc;   // lb
        s4.w = mkidx(irbr, iltc); f4.w = wrbr * wltc;   // rt
        ((short4*)sidx)[pp * 9 + n] = s4;
        ((float4*)sw4)[pp * 9 + n] = f4;
        m_lds[n * 64 + pp] = fast_sigmoid(mraw);
    }
    __syncthreads();

    // ---------------- Phase 2: 576-ch conv + sample + contraction ----------------
    float oacc[16];
    #pragma unroll
    for (int k = 0; k < 16; ++k) oacc[k] = 0.0f;

    const int c_l = tid >> 4, q = tid & 15;
    const int prow = (q >> 2) * 2, pcol = (q & 3) * 2;   // 2x2 quad origin in tile

    #pragma unroll 1
    for (int chunk = 0; chunk < 4; ++chunk) {
        const int c0 = chunk * 16;
        const int c = c0 + c_l;
        float ac[9][4];
        #pragma unroll
        for (int n = 0; n < 9; ++n) {
            float bc = b_c[c * 9 + n];
            ac[n][0] = bc; ac[n][1] = bc; ac[n][2] = bc; ac[n][3] = bc;
        }
        // ---- step A: conv, thread = (c, 2x2 quad), 9 n at once ----
        #pragma unroll 1
        for (int ci = 0; ci < 64; ++ci) {
            __syncthreads();
            for (int i = tid; i < 1296; i += 256) {
                int row = i / 9, tap = i - row * 9;
                wslice[i] = w_c[(c0 * 9 + row) * 576 + ci * 9 + tap];
            }
            __syncthreads();
            float v[4][4];
            const float* ft = &fused_t[ci * 100 + prow * 10 + pcol];
            #pragma unroll
            for (int r = 0; r < 4; ++r)
                #pragma unroll
                for (int cc = 0; cc < 4; ++cc)
                    v[r][cc] = ft[r * 10 + cc];
            const float* ws = &wslice[c_l * 81];
            #pragma unroll
            for (int kh = 0; kh < 3; ++kh)
            #pragma unroll
            for (int kw = 0; kw < 3; ++kw) {
                int tap = kh * 3 + kw;
                #pragma unroll
                for (int n = 0; n < 9; ++n) {
                    float w = ws[n * 9 + tap];
                    ac[n][0] += w * v[kh][kw];
                    ac[n][1] += w * v[kh][kw + 1];
                    ac[n][2] += w * v[kh + 1][kw];
                    ac[n][3] += w * v[kh + 1][kw + 1];
                }
            }
        }
        // ---- A-build: tanh + bilinear sample + modulate ----
        {
            const float* xp = x + (((size_t)bb * 64 + c) << 14);
            #pragma unroll
            for (int n = 0; n < 9; ++n)
            #pragma unroll
            for (int pi = 0; pi < 4; ++pi) {
                int pp = (prow + (pi >> 1)) * 8 + pcol + (pi & 1);
                short4 s4 = ((short4*)sidx)[pp * 9 + n];
                float4 f4 = ((float4*)sw4)[pp * 9 + n];
                float samp = 0.0f;
                if (s4.x >= 0) samp += f4.x * xp[s4.x];
                if (s4.y >= 0) samp += f4.y * xp[s4.y];
                if (s4.z >= 0) samp += f4.z * xp[s4.z];
                if (s4.w >= 0) samp += f4.w * xp[s4.w];
                ac[n][pi] = m_lds[n * 64 + pp] * (samp + fast_tanh(ac[n][pi]));
            }
        }
        // ---- step B: per-c exchange + contraction with w_conv ----
        #pragma unroll 1
        for (int cl2 = 0; cl2 < 16; ++cl2) {
            __syncthreads();
            if (c_l == cl2) {
                #pragma unroll
                for (int n = 0; n < 9; ++n)
                #pragma unroll
                for (int pi = 0; pi < 4; ++pi) {
                    int pp = (prow + (pi >> 1)) * 8 + pcol + (pi & 1);
                    aslice[n * 64 + pp] = ac[n][pi];
                }
            }
            for (int i = tid; i < 576; i += 256) {
                int oc = i / 9, n = i - oc * 9;
                wcv[i] = w_conv[oc * 576 + (c0 + cl2) * 9 + n];
            }
            __syncthreads();
            int g2 = tid >> 6;
            #pragma unroll
            for (int n = 0; n < 9; ++n) {
                float a = aslice[n * 64 + pix];
                #pragma unroll
                for (int k = 0; k < 16; ++k)
                    oacc[k] += wcv[(g2 * 16 + k) * 9 + n] * a;
            }
        }
    }

    // ---------------- epilogue ----------------
    {
        int g2 = tid >> 6;
        size_t obase = ((size_t)bb * 64) << 14;
        int sp = (h0 + py) * 128 + (w0 + px);
        #pragma unroll
        for (int k = 0; k < 16; ++k) {
            int oc = g2 * 16 + k;
            out[obase + ((size_t)oc << 14) + sp] = oacc[k];
        }
    }
}

extern "C" void kernel_launch(void* const* d_in, const int* in_sizes, int n_in,
                              void* d_out, int out_size, void* d_ws, size_t ws_size,
                              hipStream_t stream) {
    const float* x      = (const float*)d_in[0];
    const float* ref    = (const float*)d_in[1];
    const float* w_cd   = (const float*)d_in[2];
    const float* b_cd   = (const float*)d_in[3];
    const float* w_p    = (const float*)d_in[4];
    const float* b_p    = (const float*)d_in[5];
    const float* w_m    = (const float*)d_in[6];
    const float* b_m    = (const float*)d_in[7];
    const float* w_c    = (const float*)d_in[8];
    const float* b_c    = (const float*)d_in[9];
    const float* w_conv = (const float*)d_in[10];
    float* out = (float*)d_out;
    dim3 grid(16, 16, 4), block(256, 1, 1);
    hipLaunchKernelGGL(cdc_kernel, grid, block, 0, stream,
                       x, ref, w_cd, b_cd, w_p, b_p, w_m, b_m, w_c, b_c, w_conv, out);
}

// Round 2
// 614.067 us; speedup vs baseline: 2.6676x; 2.6676x over previous
//
#include <hip/hip_runtime.h>

// ColorDeformConv2d — round 2: bf16-MFMA rewrite (32x32x16), fp32 sampling.
// B=4, C=64, H=W=128, OUTC=64, KS=3, N=9. Block = 8x8 pixel tile, 256 thr.
//
// prep kernel: fp32->bf16 weight repack into d_ws:
//   w_c_bf  [576][576] @elem 0        (row = c*9+n, k = ci*9+tap)
//   w_pm_bf [64][576]  @elem 331776   (rows 0-17 w_p, 18-26 w_m, rest 0)
//   w_conv_bf [64][576]@elem 368640
//   w_cd_bf [64][128]  @elem 405504
// main kernel per block:
//   P0: stage B0 = concat(x,ref) 10x10-halo bf16 (frag order), GEMM0 (M=64,K=128,
//       N=100->128) -> fused bf16 in LDS.
//   P1: combined GEMM (M=640 = 576 color rows + 64 offset/mask rows, K=576,
//       N=64 pix). B-slices im2col'd from fused into LDS frag-order, A-frags
//       loaded straight from global bf16. acc = 10 f32x16 tiles/wave.
//   P2: offset/mask rows -> bilinear tables (fp32, same math as round 1).
//   P3: per m-tile: +bias, tanh, bilinear-sample x (fp32), *sigmoid(m), ->bf16
//       B2 slices; GEMM2 (w_conv) accumulates out.
//
// MFMA 32x32x16 layouts used (gfx950): A: m=lane&31, k=(lane>>5)*8+j (j=0..7
// contiguous); B: n=lane&31, k=(lane>>5)*8+j; C/D: col=lane&31,
// row=(reg&3)+8*(reg>>2)+4*(lane>>5)  [measured: learn_hip m74/m101].

typedef __attribute__((ext_vector_type(8))) __bf16 bf16x8;
typedef __attribute__((ext_vector_type(16))) float f32x16;

#define MFMA32(a, b, c) __builtin_amdgcn_mfma_f32_32x32x16_bf16((a), (b), (c), 0, 0, 0)

__device__ __forceinline__ unsigned short f2bf(float f) {
    unsigned u = __float_as_uint(f);
    return (unsigned short)((u + 0x7FFFu + ((u >> 16) & 1u)) >> 16);   // RNE
}
__device__ __forceinline__ float fast_rcp(float x) {
#if __has_builtin(__builtin_amdgcn_rcpf)
    return __builtin_amdgcn_rcpf(x);
#else
    return 1.0f / x;
#endif
}
__device__ __forceinline__ float fast_tanh(float x) {
    float t = __expf(2.0f * x);
    return 1.0f - 2.0f * fast_rcp(t + 1.0f);
}
__device__ __forceinline__ float fast_sigmoid(float x) {
    return fast_rcp(1.0f + __expf(-x));
}
__device__ __forceinline__ short mkidx(int r, int c) {
    return (r >= 1 && r <= 128 && c >= 1 && c <= 128) ? (short)(((r - 1) << 7) + (c - 1))
                                                      : (short)-1;
}

// ---------------- prep: fp32 -> bf16 weight repack ----------------
__global__ void prep_kernel(const float* __restrict__ w_c, const float* __restrict__ w_p,
                            const float* __restrict__ w_m, const float* __restrict__ w_conv,
                            const float* __restrict__ w_cd, unsigned short* __restrict__ ws) {
    int i = blockIdx.x * 256 + threadIdx.x;
    if (i < 331776) ws[i] = f2bf(w_c[i]);
    int j = i - 331776;
    if (j >= 0 && j < 36864) {
        int row = j / 576, k = j - row * 576;
        float v = 0.0f;
        if (row < 18) v = w_p[row * 576 + k];
        else if (row < 27) v = w_m[(row - 18) * 576 + k];
        ws[331776 + j] = f2bf(v);
    }
    int l2 = i - 368640;
    if (l2 >= 0 && l2 < 36864) ws[368640 + l2] = f2bf(w_conv[l2]);
    int m2 = i - 405504;
    if (m2 >= 0 && m2 < 8192) ws[405504 + m2] = f2bf(w_cd[m2]);
}

// ---------------- main ----------------
__global__ __launch_bounds__(256, 2)
void cdc_main(const float* __restrict__ x, const float* __restrict__ ref,
              const float* __restrict__ b_cd, const float* __restrict__ b_p,
              const float* __restrict__ b_m, const float* __restrict__ b_c,
              const unsigned short* __restrict__ wsbf, float* __restrict__ out)
{
    __shared__ __align__(16) char lds[45568];
    unsigned short* fused = (unsigned short*)lds;   // [64 ci][100 pos] bf16
    char* B0   = lds + 12800;                       // P0: 32768 B frag-order
    char* Bbuf = lds + 12800;                       // P1: 4 slices x 2048 B
    char* B2   = lds + 12800;                       // P3: 4 slices x 2048 B
    float* u1  = (float*)(lds + 20992);             // [27][64] fp32
    short* sidx  = (short*)(lds + 27904);           // [64 pix][9 n][4] short
    float* sw4   = (float*)(lds + 32512);           // [64 pix][9 n][4] f32
    float* m_lds = (float*)(lds + 41728);           // [9 n][64 pix] f32

    const int tid = threadIdx.x;
    const int l = tid & 63;
    const int w = tid >> 6;                  // wave id
    const int bb = blockIdx.z;
    const int h0 = blockIdx.y * 8, w0 = blockIdx.x * 8;
    const int rl31 = l & 31, kh8 = (l >> 5) * 8;

    // ---------------- P0: stage B0 (halo of concat(x,ref), bf16 frag order) ----
    {
        const int n = tid & 127;
        const int khalf = tid >> 7;
        const int rr = n / 10, cc2 = n - rr * 10;          // n<100 meaningful
        const int gh = h0 - 1 + rr, gw = w0 - 1 + cc2;
        const bool nv = (n < 100) && ((unsigned)gh < 128u) && ((unsigned)gw < 128u);
        const int sp = nv ? ((gh << 7) + gw) : 0;
        const int ctn = n >> 5, nl = n & 31;
        #pragma unroll 4
        for (int kk = 0; kk < 64; ++kk) {
            int k = kk * 2 + khalf;
            const float* src = (k < 64) ? x : ref;
            float v = nv ? src[(((size_t)bb * 64 + (k & 63)) << 14) + sp] : 0.0f;
            int s = k >> 4, kl = k & 15;
            int addr = ((s * 4 + ctn) * 64 + ((kl >> 3) * 32 + nl)) * 16 + (kl & 7) * 2;
            *(unsigned short*)(B0 + addr) = f2bf(v);
        }
    }
    __syncthreads();

    // ---------------- GEMM0: fused = w_cd @ B0  (M=64,K=128,N=128) -------------
    {
        f32x16 acc0a, acc0b;
        #pragma unroll
        for (int r = 0; r < 16; ++r) { acc0a[r] = 0.0f; acc0b[r] = 0.0f; }
        const int m0 = w & 1;
        const int ctp = (w >> 1) * 2;
        const unsigned short* A0 = wsbf + 405504 + (m0 * 32 + rl31) * 128 + kh8;
        #pragma unroll
        for (int s = 0; s < 8; ++s) {
            bf16x8 a  = *(const bf16x8*)(A0 + s * 16);
            bf16x8 b0 = *(bf16x8*)(B0 + ((s * 4 + ctp) * 64 + l) * 16);
            bf16x8 b1 = *(bf16x8*)(B0 + ((s * 4 + ctp + 1) * 64 + l) * 16);
            acc0a = MFMA32(a, b0, acc0a);
            acc0b = MFMA32(a, b1, acc0b);
        }
        // epilogue: +bias, zero outside-image halo, -> fused bf16
        #pragma unroll
        for (int t = 0; t < 2; ++t) {
            int pos = (ctp + t) * 32 + rl31;
            if (pos < 100) {
                int r2 = pos / 10, c2 = pos - r2 * 10;
                int gh = h0 - 1 + r2, gw = w0 - 1 + c2;
                bool pv = ((unsigned)gh < 128u) && ((unsigned)gw < 128u);
                #pragma unroll
                for (int rg = 0; rg < 16; ++rg) {
                    int rl = (rg & 3) + 8 * (rg >> 2) + 4 * (l >> 5);
                    int ch = m0 * 32 + rl;
                    float val = pv ? ((t ? acc0b[rg] : acc0a[rg]) + b_cd[ch]) : 0.0f;
                    fused[ch * 100 + pos] = f2bf(val);
                }
            }
        }
    }

    // ---------------- P1: combined GEMM (M=640, K=576, N=64) ------------------
    const int mtb = (w >> 1) * 10;      // waves 0,1 -> m-tiles 0..9; 2,3 -> 10..19
    const int ct = w & 1;               // col-tile (pix 0-31 / 32-63)
    unsigned aoff[10];                  // per-tile A byte offsets into wsbf
    #pragma unroll
    for (int i = 0; i < 10; ++i) {
        int row = (mtb + i) * 32 + rl31;
        unsigned eo = (row < 576) ? (unsigned)(row * 576)
                                  : (unsigned)(331776 + (row - 576) * 576);
        aoff[i] = (eo + kh8) * 2;
    }
    f32x16 acc[10];
    #pragma unroll
    for (int i = 0; i < 10; ++i)
        #pragma unroll
        for (int r = 0; r < 16; ++r) acc[i][r] = 0.0f;

    const char* wsb = (const char*)wsbf;
    #pragma unroll 1
    for (int g = 0; g < 9; ++g) {
        __syncthreads();
        // build 4 B-slices (im2col from fused), slice si built by wave si
        {
            const int n = tid & 63, si = w;
            const int fb = (n >> 3) * 10 + (n & 7);
            const int ctn = n >> 5, nl = n & 31;
            char* wb = Bbuf + si * 2048 + ctn * 1024 + nl * 16;
            const int s = g * 4 + si;
            #pragma unroll
            for (int kp = 0; kp < 8; ++kp) {
                int k0 = s * 16 + kp * 2, k1 = k0 + 1;
                int ci0 = k0 / 9, tp0 = k0 - ci0 * 9;
                int ci1 = k1 / 9, tp1 = k1 - ci1 * 9;
                unsigned v0 = fused[ci0 * 100 + fb + (tp0 / 3) * 10 + (tp0 % 3)];
                unsigned v1 = fused[ci1 * 100 + fb + (tp1 / 3) * 10 + (tp1 % 3)];
                int kl = kp * 2;
                *(unsigned*)(wb + (kl >> 3) * 512 + (kl & 7) * 2) = v0 | (v1 << 16);
            }
        }
        __syncthreads();
        #pragma unroll 1
        for (int si = 0; si < 4; ++si) {
            const int s = g * 4 + si;
            bf16x8 bfrag = *(bf16x8*)(Bbuf + si * 2048 + ct * 1024 + l * 16);
            #pragma unroll
            for (int hh = 0; hh < 2; ++hh) {
                bf16x8 af[5];
                #pragma unroll
                for (int i2 = 0; i2 < 5; ++i2)
                    af[i2] = *(const bf16x8*)(wsb + aoff[hh * 5 + i2] + s * 32);
                #pragma unroll
                for (int i2 = 0; i2 < 5; ++i2)
                    acc[hh * 5 + i2] = MFMA32(af[i2], bfrag, acc[hh * 5 + i2]);
            }
        }
    }

    // ---------------- P2: offset/mask rows -> u1, bilinear tables --------------
    if (w >= 2) {                        // tile i=8 == m-tile 18 == rows 576..607
        int pix = ct * 32 + rl31;
        #pragma unroll
        for (int rg = 0; rg < 16; ++rg) {
            int rl = (rg & 3) + 8 * (rg >> 2) + 4 * (l >> 5);
            if (rl < 27) {
                float bias = (rl < 18) ? b_p[rl] : b_m[rl - 18];
                u1[rl * 64 + pix] = acc[8][rg] + bias;
            }
        }
    }
    __syncthreads();
    #pragma unroll 1
    for (int i = tid; i < 576; i += 256) {
        int pp = i & 63, n = i >> 6;
        int hh = h0 + (pp >> 3), ww = w0 + (pp & 7);
        float offr = u1[n * 64 + pp];
        float offc = u1[(9 + n) * 64 + pp];
        float mraw = u1[(18 + n) * 64 + pp];
        int nr = n / 3, nc = n - nr * 3;
        float pr = (float)(hh + nr) + offr;
        float pc = (float)(ww + nc) + offc;
        float flr = floorf(pr), flc = floorf(pc);
        float qltr = fminf(fmaxf(flr, 0.0f), 129.0f);
        float qrbr = fminf(fmaxf(flr + 1.0f, 0.0f), 129.0f);
        float qltc = fminf(fmaxf(flc, 0.0f), 129.0f);
        float qrbc = fminf(fmaxf(flc + 1.0f, 0.0f), 129.0f);
        float prc = fminf(fmaxf(pr, 0.0f), 129.0f);
        float pcc = fminf(fmaxf(pc, 0.0f), 129.0f);
        float wltr = 1.0f + qltr - prc, wrbr = 1.0f - (qrbr - prc);
        float wltc = 1.0f + qltc - pcc, wrbc = 1.0f - (qrbc - pcc);
        int iltr = (int)qltr, irbr = (int)qrbr, iltc = (int)qltc, irbc = (int)qrbc;
        short4 s4; float4 f4;
        s4.x = mkidx(iltr, iltc); f4.x = wltr * wltc;
        s4.y = mkidx(irbr, irbc); f4.y = wrbr * wrbc;
        s4.z = mkidx(iltr, irbc); f4.z = wltr * wrbc;
        s4.w = mkidx(irbr, iltc); f4.w = wrbr * wltc;
        ((short4*)sidx)[pp * 9 + n] = s4;
        ((float4*)sw4)[pp * 9 + n] = f4;
        m_lds[n * 64 + pp] = fast_sigmoid(mraw);
    }
    __syncthreads();

    // ---------------- P3: epilogue + GEMM2 (out = w_conv @ Amat) ---------------
    f32x16 oa;
    #pragma unroll
    for (int r = 0; r < 16; ++r) oa[r] = 0.0f;
    const int m2 = w >> 1, ct2 = w & 1;
    const unsigned short* A2 = wsbf + 368640 + (m2 * 32 + rl31) * 576 + kh8;
    const int pix = ct * 32 + rl31;

    #pragma unroll
    for (int it = 0; it < 10; ++it) {
        // write B2 slices: waves 0,1 -> mt=it (slices 0,1); waves 2,3 -> mt=10+it
        // (slices 2,3), only it<8 (mt 18 is offset/mask, 19 is pad)
        if ((w < 2) || (it < 8)) {
            int mt = mtb + it;
            char* wb2 = B2 + ((w >= 2) ? 2 : 0) * 2048 + ct * 1024 + rl31 * 16;
            #pragma unroll
            for (int rg = 0; rg < 16; rg += 2) {
                int rl = (rg & 3) + 8 * (rg >> 2) + 4 * (l >> 5);
                unsigned short pv[2];
                #pragma unroll
                for (int u = 0; u < 2; ++u) {
                    int r = mt * 32 + rl + u;
                    int c = r / 9, n = r - c * 9;
                    float v = acc[it][rg + u] + b_c[r];
                    float t = fast_tanh(v);
                    short4 s4 = ((short4*)sidx)[pix * 9 + n];
                    float4 f4 = ((float4*)sw4)[pix * 9 + n];
                    const float* xp = x + (((size_t)bb * 64 + c) << 14);
                    float samp = 0.0f;
                    if (s4.x >= 0) samp += f4.x * xp[s4.x];
                    if (s4.y >= 0) samp += f4.y * xp[s4.y];
                    if (s4.z >= 0) samp += f4.z * xp[s4.z];
                    if (s4.w >= 0) samp += f4.w * xp[s4.w];
                    pv[u] = f2bf(m_lds[n * 64 + pix] * (samp + t));
                }
                *(unsigned*)(wb2 + (rl >> 4) * 2048 + ((rl >> 3) & 1) * 512 + (rl & 7) * 2)
                    = (unsigned)pv[0] | ((unsigned)pv[1] << 16);
            }
        }
        __syncthreads();
        #pragma unroll
        for (int h2 = 0; h2 < 2; ++h2) {
            bf16x8 a2 = *(const bf16x8*)(A2 + (it * 32 + h2 * 16));
            bf16x8 b2 = *(bf16x8*)(B2 + h2 * 2048 + ct2 * 1024 + l * 16);
            oa = MFMA32(a2, b2, oa);
        }
        if (it < 8) {
            #pragma unroll
            for (int h2 = 0; h2 < 2; ++h2) {
                bf16x8 a2 = *(const bf16x8*)(A2 + ((10 + it) * 32 + h2 * 16));
                bf16x8 b2 = *(bf16x8*)(B2 + (2 + h2) * 2048 + ct2 * 1024 + l * 16);
                oa = MFMA32(a2, b2, oa);
            }
        }
        __syncthreads();
    }

    // ---------------- store ----------------------------------------------------
    {
        int pix2 = ct2 * 32 + rl31;
        int py2 = pix2 >> 3, px2 = pix2 & 7;
        size_t obase = ((size_t)bb * 64) << 14;
        int sp2 = (h0 + py2) * 128 + (w0 + px2);
        #pragma unroll
        for (int rg = 0; rg < 16; ++rg) {
            int rl = (rg & 3) + 8 * (rg >> 2) + 4 * (l >> 5);
            int oc = m2 * 32 + rl;
            out[obase + ((size_t)oc << 14) + sp2] = oa[rg];
        }
    }
}

extern "C" void kernel_launch(void* const* d_in, const int* in_sizes, int n_in,
                              void* d_out, int out_size, void* d_ws, size_t ws_size,
                              hipStream_t stream) {
    const float* x      = (const float*)d_in[0];
    const float* ref    = (const float*)d_in[1];
    const float* w_cd   = (const float*)d_in[2];
    const float* b_cd   = (const float*)d_in[3];
    const float* w_p    = (const float*)d_in[4];
    const float* b_p    = (const float*)d_in[5];
    const float* w_m    = (const float*)d_in[6];
    const float* b_m    = (const float*)d_in[7];
    const float* w_c    = (const float*)d_in[8];
    const float* b_c    = (const float*)d_in[9];
    const float* w_conv = (const float*)d_in[10];
    float* out = (float*)d_out;
    unsigned short* wsbf = (unsigned short*)d_ws;

    hipLaunchKernelGGL(prep_kernel, dim3(1616), dim3(256), 0, stream,
                       w_c, w_p, w_m, w_conv, w_cd, wsbf);
    dim3 grid(16, 16, 4), block(256, 1, 1);
    hipLaunchKernelGGL(cdc_main, grid, block, 0, stream,
                       x, ref, b_cd, b_p, b_m, b_c, wsbf, out);
}

// Round 3
// 410.563 us; speedup vs baseline: 3.9899x; 1.4957x over previous
//
#include <hip/hip_runtime.h>

// ColorDeformConv2d — round 3: 3-kernel pipeline, latency-focused.
// K1 prep: fp32->bf16 weight repack (as round 2).
// K2: fused = 1x1 conv over whole image -> ws as [b][pixel][ch] bf16 (pixel-major
//     so K3 halo loads are 128B-contiguous per position).
// K3: per 8x8 tile, 512 threads (8 waves), 2 blocks/CU target:
//     P1 combined GEMM (M=640,K=576,N=64), 5 m-tiles/wave (acc=80 regs);
//     tables fp32; P3 sampling (branchless gathers) + GEMM2 with k-split reduce.
//
// ws layout (elems of ushort): w_c_bf[576][576]@0, w_pm_bf[64][576]@331776,
// w_conv_bf[64][576]@368640, w_cd_bf[64][128]@405504, fused[4][16384][64]@413696.
// Total ws = 9.22 MB.

typedef __attribute__((ext_vector_type(8))) __bf16 bf16x8;
typedef __attribute__((ext_vector_type(16))) float f32x16;
#define MFMA32(a, b, c) __builtin_amdgcn_mfma_f32_32x32x16_bf16((a), (b), (c), 0, 0, 0)

#define WS_PM   331776
#define WS_CONV 368640
#define WS_CD   405504
#define WS_FUSE 413696

__device__ __forceinline__ unsigned short f2bf(float f) {
    unsigned u = __float_as_uint(f);
    return (unsigned short)((u + 0x7FFFu + ((u >> 16) & 1u)) >> 16);   // RNE
}
__device__ __forceinline__ float fast_rcp(float x) {
#if __has_builtin(__builtin_amdgcn_rcpf)
    return __builtin_amdgcn_rcpf(x);
#else
    return 1.0f / x;
#endif
}
__device__ __forceinline__ float fast_tanh(float x) {
    float t = __expf(2.0f * x);
    return 1.0f - 2.0f * fast_rcp(t + 1.0f);
}
__device__ __forceinline__ float fast_sigmoid(float x) {
    return fast_rcp(1.0f + __expf(-x));
}

// ---------------- K1: weight repack ----------------
__global__ void prep_kernel(const float* __restrict__ w_c, const float* __restrict__ w_p,
                            const float* __restrict__ w_m, const float* __restrict__ w_conv,
                            const float* __restrict__ w_cd, unsigned short* __restrict__ ws) {
    int i = blockIdx.x * 256 + threadIdx.x;
    if (i < 331776) ws[i] = f2bf(w_c[i]);
    int j = i - WS_PM;
    if (j >= 0 && j < 36864) {
        int row = j / 576, k = j - row * 576;
        float v = 0.0f;
        if (row < 18) v = w_p[row * 576 + k];
        else if (row < 27) v = w_m[(row - 18) * 576 + k];
        ws[WS_PM + j] = f2bf(v);
    }
    int l2 = i - WS_CONV;
    if (l2 >= 0 && l2 < 36864) ws[WS_CONV + l2] = f2bf(w_conv[l2]);
    int m2 = i - WS_CD;
    if (m2 >= 0 && m2 < 8192) ws[WS_CD + m2] = f2bf(w_cd[m2]);
}

// ---------------- K2: fused 1x1 conv, whole image ----------------
__global__ __launch_bounds__(256, 4)
void k2_fused(const float* __restrict__ x, const float* __restrict__ ref,
              const float* __restrict__ b_cd, const unsigned short* __restrict__ wsbf,
              unsigned short* __restrict__ fws) {
    __shared__ __align__(16) char B0[32768];       // 8 k-slices x 128 pix frag-order
    const int tid = threadIdx.x;
    const int l = tid & 63, w = tid >> 6;          // w = col-tile 0..3
    const int b = blockIdx.y;
    const int p0 = blockIdx.x * 128;
    const int rl31 = l & 31, kh8 = (l >> 5) * 8;

    #pragma unroll 4
    for (int it = 0; it < 16; ++it) {
        int id = it * 256 + tid;                   // 4096 float4 tasks
        int k = id >> 5, quad = id & 31;
        const float* src = (k < 64) ? x : ref;
        float4 v = *(const float4*)(src + ((size_t)(b * 64 + (k & 63)) << 14) + p0 + quad * 4);
        int s = k >> 4, kl = k & 15;
        char* base = B0 + s * 4096 + (kl >> 3) * 512 + (kl & 7) * 2;
        #pragma unroll
        for (int e = 0; e < 4; ++e) {
            int p = quad * 4 + e;
            float fv = (e == 0) ? v.x : (e == 1) ? v.y : (e == 2) ? v.z : v.w;
            *(unsigned short*)(base + (p >> 5) * 1024 + (p & 31) * 16) = f2bf(fv);
        }
    }
    __syncthreads();

    f32x16 acc0, acc1;
    #pragma unroll
    for (int r = 0; r < 16; ++r) { acc0[r] = 0.0f; acc1[r] = 0.0f; }
    const unsigned short* A0 = wsbf + WS_CD + rl31 * 128 + kh8;
    #pragma unroll
    for (int s = 0; s < 8; ++s) {
        bf16x8 bf = *(bf16x8*)(B0 + s * 4096 + w * 1024 + l * 16);
        bf16x8 a0 = *(const bf16x8*)(A0 + s * 16);
        bf16x8 a1 = *(const bf16x8*)(A0 + 32 * 128 + s * 16);
        acc0 = MFMA32(a0, bf, acc0);
        acc1 = MFMA32(a1, bf, acc1);
    }
    // store transposed: fws[(b*16384 + pix)*64 + ch]
    int pix = p0 + w * 32 + rl31;
    unsigned short* dst = fws + ((size_t)b * 16384 + pix) * 64;
    #pragma unroll
    for (int t = 0; t < 2; ++t)
        #pragma unroll
        for (int q = 0; q < 4; ++q) {
            int ch0 = t * 32 + q * 8 + 4 * (l >> 5);
            float v0 = (t ? acc1[q * 4 + 0] : acc0[q * 4 + 0]) + b_cd[ch0 + 0];
            float v1 = (t ? acc1[q * 4 + 1] : acc0[q * 4 + 1]) + b_cd[ch0 + 1];
            float v2 = (t ? acc1[q * 4 + 2] : acc0[q * 4 + 2]) + b_cd[ch0 + 2];
            float v3 = (t ? acc1[q * 4 + 3] : acc0[q * 4 + 3]) + b_cd[ch0 + 3];
            uint2 pk;
            pk.x = (unsigned)f2bf(v0) | ((unsigned)f2bf(v1) << 16);
            pk.y = (unsigned)f2bf(v2) | ((unsigned)f2bf(v3) << 16);
            *(uint2*)(dst + ch0) = pk;
        }
}

// ---------------- K3: main ----------------
// LDS map (bytes):
//  fusedT  @0      : 100 pos x 144 (72 ch-elems, padded from 64 for bank spread)
//  stage   @14400  : 16384  (P1: Bbuf 4x2048; P3: B2 4x4096; end: oa-reduce 16K)
//  u1      @30784  : 27x64 f32
//  sidxL   @37696  : 64x9 short4
//  sw4L    @42304  : 64x9 float4
//  m_ldsL  @51520  : 9x64 f32
//  bcL     @53824  : 576 f32
__global__ __launch_bounds__(512, 4)
void k3_main(const float* __restrict__ x, const float* __restrict__ b_p,
             const float* __restrict__ b_m, const float* __restrict__ b_c,
             const unsigned short* __restrict__ wsbf, float* __restrict__ out) {
    __shared__ __align__(16) char lds[56128];
    char*  stage  = lds + 14400;
    float* u1     = (float*)(lds + 30784);
    short* sidxL  = (short*)(lds + 37696);
    float* sw4L   = (float*)(lds + 42304);
    float* m_ldsL = (float*)(lds + 51520);
    float* bcL    = (float*)(lds + 53824);

    const int tid = threadIdx.x;
    const int l = tid & 63;
    const int w = tid >> 6;                 // 0..7
    const int mg = w >> 1, ct = w & 1;
    const int rl31 = l & 31, kh8 = (l >> 5) * 8;
    const int bb = blockIdx.z, h0 = blockIdx.y * 8, w0 = blockIdx.x * 8;

    // ---- phase A: fused halo (coalesced from ws) + b_c to LDS ----
    {
        const unsigned short* fws = wsbf + WS_FUSE + ((size_t)bb << 14) * 64;
        #pragma unroll 2
        for (int i = tid; i < 800; i += 512) {
            int pos = i >> 3, seg = i & 7;
            int r = pos / 10, c = pos - r * 10;
            int gh = h0 - 1 + r, gw = w0 - 1 + c;
            uint4 v = make_uint4(0u, 0u, 0u, 0u);
            if ((unsigned)gh < 128u && (unsigned)gw < 128u)
                v = *(const uint4*)(fws + ((gh << 7) + gw) * 64 + seg * 8);
            *(uint4*)(lds + pos * 144 + seg * 16) = v;
        }
        #pragma unroll 2
        for (int i = tid; i < 576; i += 512) bcL[i] = b_c[i];
    }
    __syncthreads();

    // ---- P1: combined GEMM, 5 m-tiles per wave ----
    unsigned aoff[5];
    #pragma unroll
    for (int i = 0; i < 5; ++i) {
        int row = (mg * 5 + i) * 32 + rl31;
        if (row >= 608) row -= 32;          // tile 19 -> dup tile 18 (discarded)
        unsigned eo = (row < 576) ? (unsigned)(row * 576)
                                  : (unsigned)(WS_PM + (row - 576) * 576);
        aoff[i] = (eo + kh8) * 2;
    }
    f32x16 acc[5];
    #pragma unroll
    for (int i = 0; i < 5; ++i)
        #pragma unroll
        for (int r = 0; r < 16; ++r) acc[i][r] = 0.0f;

    const int bsi = tid >> 7, bpix = (tid >> 1) & 63, bhf = tid & 1;
    const int bfb = (bpix >> 3) * 10 + (bpix & 7);
    char* bwr = stage + bsi * 2048 + (bpix >> 5) * 1024 + bhf * 512 + (bpix & 31) * 16;
    const char* wsb = (const char*)wsbf;

    #pragma unroll 1
    for (int g = 0; g < 9; ++g) {
        __syncthreads();
        {   // B-build: 1 task/thread = 8 consecutive k for one pixel
            int kbase = (g * 4 + bsi) * 16 + bhf * 8;
            unsigned short tmp[8];
            #pragma unroll
            for (int j = 0; j < 8; ++j) {
                int k = kbase + j;
                int ci = k / 9, tap = k - ci * 9;
                int th = tap / 3, tw = tap - th * 3;
                int pos = bfb + th * 10 + tw;
                tmp[j] = *(unsigned short*)(lds + pos * 144 + ci * 2);
            }
            uint4 pk;
            pk.x = (unsigned)tmp[0] | ((unsigned)tmp[1] << 16);
            pk.y = (unsigned)tmp[2] | ((unsigned)tmp[3] << 16);
            pk.z = (unsigned)tmp[4] | ((unsigned)tmp[5] << 16);
            pk.w = (unsigned)tmp[6] | ((unsigned)tmp[7] << 16);
            *(uint4*)bwr = pk;
        }
        __syncthreads();
        #pragma unroll 1
        for (int si = 0; si < 4; ++si) {
            bf16x8 bfrag = *(bf16x8*)(stage + si * 2048 + ct * 1024 + l * 16);
            int sofs = (g * 4 + si) * 32;
            #pragma unroll
            for (int i = 0; i < 5; ++i) {
                if (mg * 5 + i < 19) {
                    bf16x8 af = *(const bf16x8*)(wsb + aoff[i] + sofs);
                    acc[i] = MFMA32(af, bfrag, acc[i]);
                }
            }
        }
    }

    // ---- offset/mask rows -> u1 (mg3 owns tile 18 = acc[3]) ----
    if (mg == 3) {
        int pix = ct * 32 + rl31;
        #pragma unroll
        for (int rg = 0; rg < 16; ++rg) {
            int rl = (rg & 3) + 8 * (rg >> 2) + 4 * (l >> 5);
            if (rl < 27) {
                float bias = (rl < 18) ? b_p[rl] : b_m[rl - 18];
                u1[rl * 64 + pix] = acc[3][rg] + bias;
            }
        }
    }
    __syncthreads();

    // ---- tables: fp32 positions, branchless corner weights ----
    #pragma unroll 2
    for (int i = tid; i < 576; i += 512) {
        int pp = i & 63, n = i >> 6;
        int hh = h0 + (pp >> 3), ww = w0 + (pp & 7);
        float offr = u1[n * 64 + pp];
        float offc = u1[(9 + n) * 64 + pp];
        float mraw = u1[(18 + n) * 64 + pp];
        int nr = n / 3, nc = n - nr * 3;
        float pr = (float)(hh + nr) + offr;
        float pc = (float)(ww + nc) + offc;
        float flr = floorf(pr), flc = floorf(pc);
        float qltr = fminf(fmaxf(flr, 0.0f), 129.0f);
        float qrbr = fminf(fmaxf(flr + 1.0f, 0.0f), 129.0f);
        float qltc = fminf(fmaxf(flc, 0.0f), 129.0f);
        float qrbc = fminf(fmaxf(flc + 1.0f, 0.0f), 129.0f);
        float prc = fminf(fmaxf(pr, 0.0f), 129.0f);
        float pcc = fminf(fmaxf(pc, 0.0f), 129.0f);
        float wltr = 1.0f + qltr - prc, wrbr = 1.0f - (qrbr - prc);
        float wltc = 1.0f + qltc - pcc, wrbc = 1.0f - (qrbc - pcc);
        int iltr = (int)qltr, irbr = (int)qrbr, iltc = (int)qltc, irbc = (int)qrbc;
        // branchless: OOB corner -> weight 0, index clamped to 0
        short4 s4; float4 f4;
        bool vlt_r = (iltr >= 1) && (iltr <= 128), vrb_r = (irbr >= 1) && (irbr <= 128);
        bool vlt_c = (iltc >= 1) && (iltc <= 128), vrb_c = (irbc >= 1) && (irbc <= 128);
        s4.x = (vlt_r && vlt_c) ? (short)(((iltr - 1) << 7) + (iltc - 1)) : (short)0;
        f4.x = (vlt_r && vlt_c) ? wltr * wltc : 0.0f;
        s4.y = (vrb_r && vrb_c) ? (short)(((irbr - 1) << 7) + (irbc - 1)) : (short)0;
        f4.y = (vrb_r && vrb_c) ? wrbr * wrbc : 0.0f;
        s4.z = (vlt_r && vrb_c) ? (short)(((iltr - 1) << 7) + (irbc - 1)) : (short)0;
        f4.z = (vlt_r && vrb_c) ? wltr * wrbc : 0.0f;
        s4.w = (vrb_r && vlt_c) ? (short)(((irbr - 1) << 7) + (iltc - 1)) : (short)0;
        f4.w = (vrb_r && vlt_c) ? wrbr * wltc : 0.0f;
        ((short4*)sidxL)[pp * 9 + n] = s4;
        ((float4*)sw4L)[pp * 9 + n] = f4;
        m_ldsL[n * 64 + pp] = fast_sigmoid(mraw);
    }
    __syncthreads();

    // ---- P3: sample+modulate -> B2, GEMM2 (k-split across waves) ----
    f32x16 oa;
    #pragma unroll
    for (int r = 0; r < 16; ++r) oa[r] = 0.0f;
    const int m2 = (w >> 2) & 1, ks = (w >> 1) & 1, ct2 = w & 1;
    const unsigned short* A2 = wsbf + WS_CONV + (m2 * 32 + rl31) * 576 + ks * 16 + kh8;
    const int spix = ct * 32 + rl31;
    const float* xb = x + (((size_t)bb * 64) << 14);
    char* wb2 = stage + mg * 4096 + ct * 1024 + rl31 * 16;

    #pragma unroll
    for (int it = 0; it < 5; ++it) {
        if (mg < 3 || it < 3) {
            int tile = mg * 5 + it;
            #pragma unroll
            for (int rg = 0; rg < 16; rg += 2) {
                int rl = (rg & 3) + 8 * (rg >> 2) + 4 * (l >> 5);
                int r0 = tile * 32 + rl;
                unsigned short pv[2];
                #pragma unroll
                for (int u = 0; u < 2; ++u) {
                    int r = r0 + u;
                    int c = r / 9, n = r - c * 9;
                    float v = acc[it][rg + u] + bcL[r];
                    float t = fast_tanh(v);
                    short4 s4 = ((short4*)sidxL)[spix * 9 + n];
                    float4 f4 = ((float4*)sw4L)[spix * 9 + n];
                    const float* xp = xb + ((size_t)c << 14);
                    float samp = f4.x * xp[s4.x] + f4.y * xp[s4.y]
                               + f4.z * xp[s4.z] + f4.w * xp[s4.w];
                    pv[u] = f2bf(m_ldsL[n * 64 + spix] * (samp + t));
                }
                *(unsigned*)(wb2 + (rl >> 4) * 2048 + ((rl >> 3) & 1) * 512 + (rl & 7) * 2)
                    = (unsigned)pv[0] | ((unsigned)pv[1] << 16);
            }
        }
        __syncthreads();
        int nsl = (it < 3) ? 4 : 3;
        #pragma unroll
        for (int mgp = 0; mgp < 4; ++mgp) {
            if (mgp < nsl) {
                bf16x8 a2 = *(const bf16x8*)(A2 + (mgp * 5 + it) * 32);
                bf16x8 b2 = *(bf16x8*)(stage + mgp * 4096 + ks * 2048 + ct2 * 1024 + l * 16);
                oa = MFMA32(a2, b2, oa);
            }
        }
        __syncthreads();
    }

    // ---- reduce k-halves + store ----
    float* red = (float*)stage;
    if (ks == 1) {
        #pragma unroll
        for (int rg = 0; rg < 16; ++rg)
            red[((m2 * 2 + ct2) * 64 + l) * 16 + rg] = oa[rg];
    }
    __syncthreads();
    if (ks == 0) {
        int pix2 = ct2 * 32 + rl31;
        size_t obase = ((size_t)bb * 64) << 14;
        int sp2 = (h0 + (pix2 >> 3)) * 128 + w0 + (pix2 & 7);
        #pragma unroll
        for (int rg = 0; rg < 16; ++rg) {
            int rl = (rg & 3) + 8 * (rg >> 2) + 4 * (l >> 5);
            int oc = m2 * 32 + rl;
            out[obase + ((size_t)oc << 14) + sp2]
                = oa[rg] + red[((m2 * 2 + ct2) * 64 + l) * 16 + rg];
        }
    }
}

extern "C" void kernel_launch(void* const* d_in, const int* in_sizes, int n_in,
                              void* d_out, int out_size, void* d_ws, size_t ws_size,
                              hipStream_t stream) {
    const float* x      = (const float*)d_in[0];
    const float* ref    = (const float*)d_in[1];
    const float* w_cd   = (const float*)d_in[2];
    const float* b_cd   = (const float*)d_in[3];
    const float* w_p    = (const float*)d_in[4];
    const float* b_p    = (const float*)d_in[5];
    const float* w_m    = (const float*)d_in[6];
    const float* b_m    = (const float*)d_in[7];
    const float* w_c    = (const float*)d_in[8];
    const float* b_c    = (const float*)d_in[9];
    const float* w_conv = (const float*)d_in[10];
    float* out = (float*)d_out;
    unsigned short* wsbf = (unsigned short*)d_ws;

    hipLaunchKernelGGL(prep_kernel, dim3(1616), dim3(256), 0, stream,
                       w_c, w_p, w_m, w_conv, w_cd, wsbf);
    hipLaunchKernelGGL(k2_fused, dim3(128, 4), dim3(256), 0, stream,
                       x, ref, b_cd, wsbf, wsbf + WS_FUSE);
    hipLaunchKernelGGL(k3_main, dim3(16, 16, 4), dim3(512), 0, stream,
                       x, b_p, b_m, b_c, wsbf, out);
}

// Round 4
// 398.391 us; speedup vs baseline: 4.1118x; 1.0306x over previous
//
#include <hip/hip_runtime.h>
#include <hip/hip_fp16.h>

// ColorDeformConv2d — round 4: GEMM-decomposed pipeline.
// prep: repack weights into MFMA frag-order bf16 (k reordered tap-major: k'=tap*64+ci)
// k2:   fused = 1x1 conv (MFMA), writes fused2 channel-major bf16 [b][ch][16384]
// k_pm: offset/mask GEMM (M=32,K=576,N=128/block), writes u bf16 [27][b][16384]
// k3:   per (m-chunk 128 rows, image row h, b): tables from u; U-GEMM 128x128
//       (18 k-chunks, A staged frag-order, B im2col-staged from fused2);
//       epilogue tanh+bilinear-sample+modulate in regs; scatter to LDS B-frags;
//       out-GEMM with w_conv; unsafeAtomicAdd into zeroed out.
//
// ws (u16 elems): A_c[20mt][36ks][64l][8] @0 (368640), A_pm @368640 (18432),
// A_conv[2][40][64][8] @387072 (40960), Wcd row-major @428032 (8192),
// fused2 @436224 (4*64*16384), u bf16 @4630528 (27*65536). Total 12.8 MB.

typedef __attribute__((ext_vector_type(8))) __bf16 bf16x8;
typedef __attribute__((ext_vector_type(16))) float f32x16;
#define MFMA32(a, b, c) __builtin_amdgcn_mfma_f32_32x32x16_bf16((a), (b), (c), 0, 0, 0)

#define WS_AC    0
#define WS_APM   368640
#define WS_ACONV 387072
#define WS_WCD   428032
#define WS_F2    436224
#define WS_U     4630528

__device__ __forceinline__ unsigned short f2bf(float f) {
    unsigned u = __float_as_uint(f);
    return (unsigned short)((u + 0x7FFFu + ((u >> 16) & 1u)) >> 16);   // RNE
}
__device__ __forceinline__ float bf2f(unsigned short s) {
    return __uint_as_float(((unsigned)s) << 16);
}
__device__ __forceinline__ float fast_rcp(float x) {
#if __has_builtin(__builtin_amdgcn_rcpf)
    return __builtin_amdgcn_rcpf(x);
#else
    return 1.0f / x;
#endif
}
__device__ __forceinline__ float fast_tanh(float x) {
    float t = __expf(2.0f * x);
    return 1.0f - 2.0f * fast_rcp(t + 1.0f);
}
__device__ __forceinline__ float fast_sigmoid(float x) {
    return fast_rcp(1.0f + __expf(-x));
}

// ---------------- prep: weight repack to frag-order bf16 ----------------
__global__ void prep_kernel(const float* __restrict__ w_c, const float* __restrict__ w_p,
                            const float* __restrict__ w_m, const float* __restrict__ w_conv,
                            const float* __restrict__ w_cd, unsigned short* __restrict__ ws) {
    int i = blockIdx.x * 256 + threadIdx.x;
    if (i >= 436224) return;
    float val;
    if (i < WS_APM) {                       // A_c: row=gmt*32+(l&31), k'=ks*16+(l>>5)*8+j
        int t = i, j = t & 7, l = (t >> 3) & 63, r = t >> 9, ks = r % 36, gmt = r / 36;
        int row = gmt * 32 + (l & 31);
        int kp = ks * 16 + (l >> 5) * 8 + j, tap = kp >> 6, ci = kp & 63;
        val = (row < 576) ? w_c[row * 576 + ci * 9 + tap] : 0.0f;
    } else if (i < WS_ACONV) {              // A_pm: rows 0-17 w_p, 18-26 w_m
        int t = i - WS_APM, j = t & 7, l = (t >> 3) & 63, ks = t >> 9;
        int row = l & 31;
        int kp = ks * 16 + (l >> 5) * 8 + j, tap = kp >> 6, ci = kp & 63;
        val = (row < 18) ? w_p[row * 576 + ci * 9 + tap]
            : (row < 27) ? w_m[(row - 18) * 576 + ci * 9 + tap] : 0.0f;
    } else if (i < WS_WCD) {                // A_conv: k = U-row (natural order)
        int t = i - WS_ACONV, j = t & 7, l = (t >> 3) & 63, r = t >> 9;
        int gks = r % 40, ocT = r / 40;
        int oc = ocT * 32 + (l & 31);
        int krow = gks * 16 + (l >> 5) * 8 + j;
        val = (krow < 576) ? w_conv[oc * 576 + krow] : 0.0f;
    } else {                                // Wcd row-major [64][128]
        val = w_cd[i - WS_WCD];
    }
    ws[i] = f2bf(val);
}

// ---------------- shared: im2col B-stage (32 k' x 128 px, frag-order) ------
template <int TPB>
__device__ __forceinline__ void stage_B(char* Bst, const unsigned short* f2b,
                                        int h, int chunk, int tid) {
    int tap = chunk >> 1, cih = (chunk & 1) * 32;
    int dh = tap / 3 - 1, dw = tap % 3 - 1;
    int hs = h + dh;
    #pragma unroll
    for (int it = 0; it < 512 / TPB; ++it) {
        int task = it * TPB + tid;          // 512 tasks: kg(4) x px(128)
        int kg = task >> 7, px = task & 127;
        int wsrc = px + dw;
        unsigned short v[8];
        if (((unsigned)hs < 128u) && ((unsigned)wsrc < 128u)) {
            const unsigned short* r = f2b + ((cih + kg * 8) << 14) + (hs << 7) + wsrc;
            #pragma unroll
            for (int j = 0; j < 8; ++j) v[j] = r[j << 14];
        } else {
            #pragma unroll
            for (int j = 0; j < 8; ++j) v[j] = 0;
        }
        uint4 pk;
        pk.x = (unsigned)v[0] | ((unsigned)v[1] << 16);
        pk.y = (unsigned)v[2] | ((unsigned)v[3] << 16);
        pk.z = (unsigned)v[4] | ((unsigned)v[5] << 16);
        pk.w = (unsigned)v[6] | ((unsigned)v[7] << 16);
        *(uint4*)(Bst + ((kg >> 1) * 4 + (px >> 5)) * 1024
                      + ((px & 31) + 32 * (kg & 1)) * 16) = pk;
    }
}

// ---------------- k2: fused 1x1 conv -> fused2 channel-major ----------------
__global__ __launch_bounds__(256, 4)
void k2_fused(const float* __restrict__ x, const float* __restrict__ ref,
              const float* __restrict__ b_cd, const unsigned short* __restrict__ wsbf,
              unsigned short* __restrict__ ws) {
    __shared__ __align__(16) char B0[32768];
    const int tid = threadIdx.x, l = tid & 63, w = tid >> 6;
    const int b = blockIdx.y, p0 = blockIdx.x * 128;
    const int rl31 = l & 31, kh8 = (l >> 5) * 8;

    #pragma unroll
    for (int it = 0; it < 8; ++it) {        // 2048 tasks: kg(16) x px(128)
        int task = it * 256 + tid;
        int kg = task >> 7, px = task & 127;
        const float* src = (kg < 8) ? x : ref;
        int kbase = (kg & 7) * 8;
        unsigned short v[8];
        #pragma unroll
        for (int j = 0; j < 8; ++j)
            v[j] = f2bf(src[(((size_t)b * 64 + kbase + j) << 14) + p0 + px]);
        uint4 pk;
        pk.x = (unsigned)v[0] | ((unsigned)v[1] << 16);
        pk.y = (unsigned)v[2] | ((unsigned)v[3] << 16);
        pk.z = (unsigned)v[4] | ((unsigned)v[5] << 16);
        pk.w = (unsigned)v[6] | ((unsigned)v[7] << 16);
        *(uint4*)(B0 + ((kg >> 1) * 4 + (px >> 5)) * 1024
                      + ((px & 31) + 32 * (kg & 1)) * 16) = pk;
    }
    __syncthreads();

    f32x16 a0, a1;
    #pragma unroll
    for (int r = 0; r < 16; ++r) { a0[r] = 0.0f; a1[r] = 0.0f; }
    const unsigned short* A0 = wsbf + WS_WCD + rl31 * 128 + kh8;
    #pragma unroll
    for (int s = 0; s < 8; ++s) {
        bf16x8 bf = *(bf16x8*)(B0 + ((s * 4 + w) * 64 + l) * 16);
        bf16x8 x0 = *(const bf16x8*)(A0 + s * 16);
        bf16x8 x1 = *(const bf16x8*)(A0 + 32 * 128 + s * 16);
        a0 = MFMA32(x0, bf, a0);
        a1 = MFMA32(x1, bf, a1);
    }
    unsigned short* f2 = ws + WS_F2 + ((size_t)b << 20);
    int px = p0 + w * 32 + rl31;
    #pragma unroll
    for (int t = 0; t < 2; ++t)
        #pragma unroll
        for (int reg = 0; reg < 16; ++reg) {
            int rl = (reg & 3) + 8 * (reg >> 2) + 4 * (l >> 5);
            int ch = t * 32 + rl;
            float v = (t ? a1[reg] : a0[reg]) + b_cd[ch];
            f2[(ch << 14) + px] = f2bf(v);
        }
}

// ---------------- k_pm: offset/mask GEMM -> u bf16 ----------------
__global__ __launch_bounds__(256, 4)
void k_pm(const float* __restrict__ b_p, const float* __restrict__ b_m,
          const unsigned short* __restrict__ wsbf, unsigned short* __restrict__ ws) {
    __shared__ __align__(16) char Bst[8192];
    const int tid = threadIdx.x, l = tid & 63, w = tid >> 6;
    const int h = blockIdx.x, b = blockIdx.y;
    const unsigned short* f2b = wsbf + WS_F2 + ((size_t)b << 20);

    f32x16 acc;
    #pragma unroll
    for (int r = 0; r < 16; ++r) acc[r] = 0.0f;
    #pragma unroll 1
    for (int chunk = 0; chunk < 18; ++chunk) {
        __syncthreads();
        stage_B<256>(Bst, f2b, h, chunk, tid);
        __syncthreads();
        #pragma unroll
        for (int s = 0; s < 2; ++s) {
            bf16x8 bf = *(bf16x8*)(Bst + ((s * 4 + w) * 64 + l) * 16);
            bf16x8 af = *(const bf16x8*)(wsbf + WS_APM + (((chunk * 2 + s) * 64 + l) << 3));
            acc = MFMA32(af, bf, acc);
        }
    }
    int px = w * 32 + (l & 31);
    unsigned short* up = ws + WS_U + b * 16384 + h * 128 + px;
    #pragma unroll
    for (int reg = 0; reg < 16; ++reg) {
        int rl = (reg & 3) + 8 * (reg >> 2) + 4 * (l >> 5);
        if (rl < 27) {
            float bias = (rl < 18) ? b_p[rl] : b_m[rl - 18];
            up[rl * 65536] = f2bf(acc[reg] + bias);
        }
    }
}

// ---------------- k3: U-GEMM + sample epilogue + out-GEMM ----------------
// LDS: Ast@0 8K | Bst@8192 8K | sidx@16384 9216 | w4h@25600 9216 (f16)
//      mL@34816 4608 | bcL@39424 512.  Amod overlay @0 32K (post-epilogue).
__global__ __launch_bounds__(512, 6)
void k3_main(const float* __restrict__ x, const float* __restrict__ b_c,
             const unsigned short* __restrict__ wsbf, float* __restrict__ out) {
    __shared__ __align__(16) char lds[39936];
    char* Ast = lds;
    char* Bst = lds + 8192;
    short* sidx = (short*)(lds + 16384);
    unsigned short* w4h = (unsigned short*)(lds + 25600);
    float* mL = (float*)(lds + 34816);
    float* bcL = (float*)(lds + 39424);

    const int tid = threadIdx.x, l = tid & 63, w = tid >> 6;
    const int nT = w & 3, mTp = (w >> 2) * 2;
    const int mc = blockIdx.x, h = blockIdx.y, b = blockIdx.z;
    const unsigned short* f2b = wsbf + WS_F2 + ((size_t)b << 20);

    // ---- tables from u (fp32 math, same as verified r3) ----
    #pragma unroll 1
    for (int i = tid; i < 1152; i += 512) {
        int n = i >> 7, px = i & 127;
        int base = b * 16384 + h * 128 + px;
        float offr = bf2f(wsbf[WS_U + n * 65536 + base]);
        float offc = bf2f(wsbf[WS_U + (9 + n) * 65536 + base]);
        float mraw = bf2f(wsbf[WS_U + (18 + n) * 65536 + base]);
        int nr = n / 3, nc = n - nr * 3;
        float pr = (float)(h + nr) + offr;
        float pc = (float)(px + nc) + offc;
        float flr = floorf(pr), flc = floorf(pc);
        float qltr = fminf(fmaxf(flr, 0.0f), 129.0f);
        float qrbr = fminf(fmaxf(flr + 1.0f, 0.0f), 129.0f);
        float qltc = fminf(fmaxf(flc, 0.0f), 129.0f);
        float qrbc = fminf(fmaxf(flc + 1.0f, 0.0f), 129.0f);
        float prc = fminf(fmaxf(pr, 0.0f), 129.0f);
        float pcc = fminf(fmaxf(pc, 0.0f), 129.0f);
        float wltr = 1.0f + qltr - prc, wrbr = 1.0f - (qrbr - prc);
        float wltc = 1.0f + qltc - pcc, wrbc = 1.0f - (qrbc - pcc);
        int iltr = (int)qltr, irbr = (int)qrbr, iltc = (int)qltc, irbc = (int)qrbc;
        bool vlt_r = (iltr >= 1) && (iltr <= 128), vrb_r = (irbr >= 1) && (irbr <= 128);
        bool vlt_c = (iltc >= 1) && (iltc <= 128), vrb_c = (irbc >= 1) && (irbc <= 128);
        short4 s4; float4 f4;
        s4.x = (vlt_r && vlt_c) ? (short)(((iltr - 1) << 7) + (iltc - 1)) : (short)0;
        f4.x = (vlt_r && vlt_c) ? wltr * wltc : 0.0f;
        s4.y = (vrb_r && vrb_c) ? (short)(((irbr - 1) << 7) + (irbc - 1)) : (short)0;
        f4.y = (vrb_r && vrb_c) ? wrbr * wrbc : 0.0f;
        s4.z = (vlt_r && vrb_c) ? (short)(((iltr - 1) << 7) + (irbc - 1)) : (short)0;
        f4.z = (vlt_r && vrb_c) ? wltr * wrbc : 0.0f;
        s4.w = (vrb_r && vlt_c) ? (short)(((irbr - 1) << 7) + (iltc - 1)) : (short)0;
        f4.w = (vrb_r && vlt_c) ? wrbr * wltc : 0.0f;
        ((short4*)sidx)[px * 9 + n] = s4;
        int wb = (px * 9 + n) * 4;
        w4h[wb + 0] = __half_as_ushort(__float2half(f4.x));
        w4h[wb + 1] = __half_as_ushort(__float2half(f4.y));
        w4h[wb + 2] = __half_as_ushort(__float2half(f4.z));
        w4h[wb + 3] = __half_as_ushort(__float2half(f4.w));
        mL[n * 128 + px] = fast_sigmoid(mraw);
    }
    if (tid < 128) {
        int row = mc * 128 + tid;
        bcL[tid] = (row < 576) ? b_c[row] : 0.0f;
    }

    // ---- U-GEMM: 18 k-chunks ----
    f32x16 acc[2];
    #pragma unroll
    for (int mi = 0; mi < 2; ++mi)
        #pragma unroll
        for (int r = 0; r < 16; ++r) acc[mi][r] = 0.0f;

    #pragma unroll 1
    for (int chunk = 0; chunk < 18; ++chunk) {
        __syncthreads();
        {   // stage A: wave w stages seg w = (mT = w>>1, s = w&1)
            int gmt = mc * 4 + (w >> 1), ks = chunk * 2 + (w & 1);
            uint4 av = *(const uint4*)(wsbf + WS_AC + (((gmt * 36 + ks) * 64 + l) << 3));
            *(uint4*)(Ast + w * 1024 + l * 16) = av;
        }
        stage_B<512>(Bst, f2b, h, chunk, tid);
        __syncthreads();
        #pragma unroll
        for (int s = 0; s < 2; ++s) {
            bf16x8 bf = *(bf16x8*)(Bst + ((s * 4 + nT) * 64 + l) * 16);
            #pragma unroll
            for (int mi = 0; mi < 2; ++mi) {
                bf16x8 af = *(bf16x8*)(Ast + ((mTp + mi) * 2 + s) * 1024 + l * 16);
                acc[mi] = MFMA32(af, bf, acc[mi]);
            }
        }
    }

    // ---- epilogue: tanh + bilinear sample + modulate (in regs) ----
    const int pxe = nT * 32 + (l & 31);
    const float* xb = x + (((size_t)b * 64) << 14);
    #pragma unroll
    for (int mi = 0; mi < 2; ++mi) {
        int rowbase = mc * 128 + (mTp + mi) * 32;
        if (rowbase < 576) {
            #pragma unroll
            for (int reg = 0; reg < 16; ++reg) {
                int rl = (reg & 3) + 8 * (reg >> 2) + 4 * (l >> 5);
                int row = rowbase + rl;
                int c = row / 9, n = row - c * 9;
                float uv = acc[mi][reg] + bcL[row - mc * 128];
                float t = fast_tanh(uv);
                short4 s4 = ((short4*)sidx)[pxe * 9 + n];
                int wb = (pxe * 9 + n) * 4;
                float w0 = __half2float(__ushort_as_half(w4h[wb + 0]));
                float w1 = __half2float(__ushort_as_half(w4h[wb + 1]));
                float w2 = __half2float(__ushort_as_half(w4h[wb + 2]));
                float w3 = __half2float(__ushort_as_half(w4h[wb + 3]));
                const float* xp = xb + ((size_t)c << 14);
                float samp = w0 * xp[s4.x] + w1 * xp[s4.y] + w2 * xp[s4.z] + w3 * xp[s4.w];
                acc[mi][reg] = mL[n * 128 + pxe] * (samp + t);
            }
        } else {
            #pragma unroll
            for (int reg = 0; reg < 16; ++reg) acc[mi][reg] = 0.0f;
        }
    }
    __syncthreads();
    // ---- scatter Amod to LDS B-frag layout (overlay @0, 32K) ----
    #pragma unroll
    for (int mi = 0; mi < 2; ++mi)
        #pragma unroll
        for (int reg = 0; reg < 16; ++reg) {
            int rl = (reg & 3) + 8 * (reg >> 2) + 4 * (l >> 5);
            int k = (mTp + mi) * 32 + rl;
            *(unsigned short*)(lds + ((k >> 4) * 4 + nT) * 1024
                                   + ((l & 31) + 32 * ((k >> 3) & 1)) * 16 + (k & 7) * 2)
                = f2bf(acc[mi][reg]);
        }
    __syncthreads();
    // ---- out-GEMM: oa = w_conv_chunk @ Amod ----
    const int ocT = w >> 2, nT2 = w & 3;
    f32x16 oa;
    #pragma unroll
    for (int r = 0; r < 16; ++r) oa[r] = 0.0f;
    #pragma unroll
    for (int ks8 = 0; ks8 < 8; ++ks8) {
        bf16x8 af = *(const bf16x8*)(wsbf + WS_ACONV + (((ocT * 40 + mc * 8 + ks8) * 64 + l) << 3));
        bf16x8 bf = *(bf16x8*)(lds + (ks8 * 4 + nT2) * 1024 + l * 16);
        oa = MFMA32(af, bf, oa);
    }
    float* ob = out + (((size_t)b * 64) << 14) + h * 128 + nT2 * 32 + (l & 31);
    #pragma unroll
    for (int reg = 0; reg < 16; ++reg) {
        int rl = (reg & 3) + 8 * (reg >> 2) + 4 * (l >> 5);
        int oc = ocT * 32 + rl;
        unsafeAtomicAdd(ob + ((size_t)oc << 14), oa[reg]);
    }
}

extern "C" void kernel_launch(void* const* d_in, const int* in_sizes, int n_in,
                              void* d_out, int out_size, void* d_ws, size_t ws_size,
                              hipStream_t stream) {
    const float* x      = (const float*)d_in[0];
    const float* ref    = (const float*)d_in[1];
    const float* w_cd   = (const float*)d_in[2];
    const float* b_cd   = (const float*)d_in[3];
    const float* w_p    = (const float*)d_in[4];
    const float* b_p    = (const float*)d_in[5];
    const float* w_m    = (const float*)d_in[6];
    const float* b_m    = (const float*)d_in[7];
    const float* w_c    = (const float*)d_in[8];
    const float* b_c    = (const float*)d_in[9];
    const float* w_conv = (const float*)d_in[10];
    float* out = (float*)d_out;
    unsigned short* wsbf = (unsigned short*)d_ws;

    hipMemsetAsync(out, 0, (size_t)out_size * sizeof(float), stream);
    hipLaunchKernelGGL(prep_kernel, dim3(1704), dim3(256), 0, stream,
                       w_c, w_p, w_m, w_conv, w_cd, wsbf);
    hipLaunchKernelGGL(k2_fused, dim3(128, 4), dim3(256), 0, stream,
                       x, ref, b_cd, wsbf, wsbf);
    hipLaunchKernelGGL(k_pm, dim3(128, 4), dim3(256), 0, stream,
                       b_p, b_m, wsbf, wsbf);
    hipLaunchKernelGGL(k3_main, dim3(5, 128, 4), dim3(512), 0, stream,
                       x, b_c, wsbf, out);
}